// Round 10
// baseline (185.589 us; speedup 1.0000x reference)
//
#include <hip/hip_runtime.h>

// Problem constants (fixed by setup_inputs)
#define HW   256
#define Pp   33
#define OUTF 128
#define SIG  16

// conv1-output plane (bf16) for conv2 MFMA A-operands:
// [rowslot NSLOT][parity 2][col' 16][kc 40] ushort.
// 9-slot ring: iter i ds-READS slots (4i+1..4i+4)%9 (slot 4i is consumed from
// the register cache n*), WRITES rows 4i+6..4i+9 -> slots {4i+6,4i+7,4i+8,4i}%9.
// Read/write sets disjoint -> no mid-iteration barrier.
#define KCP   40
#define PLROW (2 * 16 * KCP)     // 1280 shorts per conv1 row
#define NSLOT 9
#define PLSZ  (NSLOT * PLROW)    // 11520 shorts = 23040 B

// ws layout (float offsets)
#define WS_W1FH 0       // [2 nt][64 lane][8 j] ushort = 512 f (conv1 B-frags hi)
#define WS_W1FL 512     // same, lo
#define WS_BHI  1024    // 18432 ushort = 9216 f (conv2 B-frags hi)
#define WS_BLO  10240   // conv2 B-frags lo
#define WS_WLT  19456   // [64][128] f32 = 8192

typedef __attribute__((ext_vector_type(8))) short v8s;    // 8 bf16
typedef __attribute__((ext_vector_type(4))) float f32x4;  // MFMA acc

__device__ __forceinline__ unsigned short f2bf_rne(float x) {
  unsigned u = __float_as_uint(x);
  unsigned r = (u + 0x7FFFu + ((u >> 16) & 1u)) >> 16;
  return (unsigned short)r;
}
__device__ __forceinline__ float bf2f(unsigned short h) {
  return __uint_as_float(((unsigned)h) << 16);
}

__global__ __launch_bounds__(256) void prep_kernel(
    const float* __restrict__ w1, const float* __restrict__ w2,
    const float* __restrict__ wl, float* __restrict__ ws,
    float* __restrict__ out) {
  int t = blockIdx.x * 256 + threadIdx.x;
  int stride = gridDim.x * 256;
  if (blockIdx.x == 0 && threadIdx.x == 0) out[0] = 0.0f;
  // conv1 B-frags: k = 8*(l>>4)+j (27-dim padded to 32), ch = 16*nt + (l&15)
  unsigned short* w1h = (unsigned short*)(ws + WS_W1FH);
  unsigned short* w1lo = (unsigned short*)(ws + WS_W1FL);
  for (int i = t; i < 1024; i += stride) {
    int j  = i & 7;
    int l  = (i >> 3) & 63;
    int nt = i >> 9;
    int k  = 8 * (l >> 4) + j;
    int ch = 16 * nt + (l & 15);
    float v = (k < 27) ? w1[ch * 27 + k] : 0.0f;
    unsigned short h = f2bf_rne(v);
    w1h[i]  = h;
    w1lo[i] = f2bf_rne(v - bf2f(h));
  }
  // conv2 B-frags: n(ch)=w*16+(l&15), k(kc)=(l>>4)*8+j, per tap
  unsigned short* bhi = (unsigned short*)(ws + WS_BHI);
  unsigned short* blo = (unsigned short*)(ws + WS_BLO);
  for (int i = t; i < 18432; i += stride) {
    int j  = i & 7;
    int l  = (i >> 3) & 63;
    int w  = (i >> 9) & 3;
    int tp = i >> 11;
    int ch = w * 16 + (l & 15);
    int kc = ((l >> 4) << 3) + j;
    int ky = tp / 3, kx = tp - ky * 3;
    float v = w2[ch * 288 + kc * 9 + ky * 3 + kx];
    unsigned short h = f2bf_rne(v);
    bhi[i] = h;
    blo[i] = f2bf_rne(v - bf2f(h));
  }
  for (int i = t; i < 8192; i += stride) {
    int o = i & 127, ii = i >> 7;
    ws[WS_WLT + i] = wl[o * 64 + ii];
  }
}

// One block per (n,b); both sides in-block; one atomicAdd.
// R10 vs R9 (numerics op-identical, absmax 0.0): patch LDS + staging DELETED.
// conv1 gathers f32 pixels straight from global (L2-resident) and converts
// with the same f2bf_rne inline. Staging wrote patch cols 0..32 real and
// 33..35 ZERO; the gather's pixel col = 16*mtl+m16+kx <= 33, so mtl=1 lanes
// apply the predicate (m16+kx <= 16) to reproduce the zero-pad bit-exactly.
// Wins: ~124 ds_read_u16 + staging ds_writes + staging barrier + staging
// latency exposure removed per wave-side; gather moves to the idle VMEM pipe
// and (having no LDS-sync dependency) can be hoisted across the conv2 MFMAs.
// LDS drops 31.2K -> ~24K.
__global__ __launch_bounds__(256) void patch_cnn_kernel(
    const float* __restrict__ imgG, const float* __restrict__ imgS,
    const float* __restrict__ kpG,  const float* __restrict__ kpS,
    const float* __restrict__ b1g,  const float* __restrict__ b2g,
    const float* __restrict__ blg,  const float* __restrict__ ws,
    float* __restrict__ out) {
  __shared__ __align__(16) unsigned short hiP[PLSZ];             // 23040 B
  __shared__ float gapv[64];
  __shared__ float fstash[OUTF];
  __shared__ float lred[4];
  // total ~= 23.8 KB

  const int bid  = blockIdx.x;          // grid 1024
  const int n    = bid >> 2;
  const int b    = bid & 3;
  const int tid  = threadIdx.x;
  const int wave = tid >> 6;
  const int lane = tid & 63;

  const int m16 = lane & 15;
  const int qq  = lane >> 4;

  // conv1 per-lane gather: A-frag element j -> k = 8*qq + j ->
  // (ci,ky,kx); global offset goff = ci*HW*HW + ky*HW + kx.
  int  goff[8];
  int  kxv[8];
  bool kval[8];
#pragma unroll
  for (int j = 0; j < 8; ++j) {
    int k = 8 * qq + j;
    kval[j] = (k < 27);
    int kk = kval[j] ? k : 0;
    int ci = kk / 9, r2 = kk - ci * 9, ky = r2 / 3, kx = r2 - ky * 3;
    goff[j] = (ci * HW + ky) * HW + kx;
    kxv[j]  = kx;
  }

  // conv1 B-frags for BOTH nt slices (each wave does all 4 tiles of its row)
  const v8s* w1fp = (const v8s*)((const unsigned short*)(ws + WS_W1FH));
  const v8s* w1lp = (const v8s*)((const unsigned short*)(ws + WS_W1FL));
  const v8s w1hF0 = w1fp[lane],      w1lF0 = w1lp[lane];
  const v8s w1hF1 = w1fp[64 + lane], w1lF1 = w1lp[64 + lane];
  const float b1v0 = b1g[m16];
  const float b1v1 = b1g[16 + m16];

  // conv2 frag pointers (L2-resident) and bias (N-split by wave)
  const v8s* bhW = (const v8s*)((const unsigned short*)(ws + WS_BHI)) + (wave * 64 + lane);
  const v8s* blW = (const v8s*)((const unsigned short*)(ws + WS_BLO)) + (wave * 64 + lane);
  const float b2v = b2g[wave * 16 + m16];

  // set per side: base pointer of the clamped patch origin
  const float* gp = nullptr;

  // wave-local conv1 for row r: gather 2 A-frags from GLOBAL, 4 MFMA tiles,
  // 16 b16 hiP writes. Values/op-order identical to the staged-patch path
  // (zero-pad reproduced by the mtl=1 predicate).
  auto conv1_row_local = [&](int r) {
    const int sl = r % NSLOT;
    const float* gr = gp + r * HW;
#pragma unroll
    for (int mtl = 0; mtl < 2; ++mtl) {
      v8s af;
#pragma unroll
      for (int j = 0; j < 8; ++j) {
        bool ok = kval[j] && (mtl == 0 || (m16 + kxv[j] <= 16));
        float v = ok ? gr[goff[j] + 16 * mtl + m16] : 0.0f;
        af[j] = (short)f2bf_rne(v);
      }
      f32x4 z = {0.f, 0.f, 0.f, 0.f};
      f32x4 t0 = __builtin_amdgcn_mfma_f32_16x16x32_bf16(af, w1hF0, z, 0, 0, 0);
      t0 = __builtin_amdgcn_mfma_f32_16x16x32_bf16(af, w1lF0, t0, 0, 0, 0);
      f32x4 t1 = __builtin_amdgcn_mfma_f32_16x16x32_bf16(af, w1hF1, z, 0, 0, 0);
      t1 = __builtin_amdgcn_mfma_f32_16x16x32_bf16(af, w1lF1, t1, 0, 0, 0);
#pragma unroll
      for (int rg = 0; rg < 4; ++rg) {
        int x = 16 * mtl + 4 * qq + rg;   // x=31 garbage, unread slot
        int rowoff = ((sl * 2 + (x & 1)) * 16 + (x >> 1)) * KCP;
        hiP[rowoff + m16]      = f2bf_rne(fmaxf(t0[rg] + b1v0, 0.f));
        hiP[rowoff + 16 + m16] = f2bf_rne(fmaxf(t1[rg] + b1v1, 0.f));
      }
    }
  };

  // conv2 A-operand load: (row-slot sk in [0,NSLOT), tap kx)
  auto ldA = [&](int sk, int kx) -> v8s {
    const int p = kx & 1;
    int cp = m16 + (kx >> 1); if (cp > 15) cp = 15;   // xo=15 is pad, discarded
    return *(const v8s*)&hiP[((sk * 2 + p) * 16 + cp) * KCP + qq * 8];
  };

// dual-row tap: chain order inside each acc identical to baseline (hi, lo)
#define TAP2(tp, aA, aB)                                                      \
  { v8s bh_ = bhW[(tp) * 256]; v8s bl_ = blW[(tp) * 256];                     \
    accA = __builtin_amdgcn_mfma_f32_16x16x32_bf16(aA, bh_, accA, 0, 0, 0);   \
    accB = __builtin_amdgcn_mfma_f32_16x16x32_bf16(aB, bh_, accB, 0, 0, 0);   \
    accA = __builtin_amdgcn_mfma_f32_16x16x32_bf16(aA, bl_, accA, 0, 0, 0);   \
    accB = __builtin_amdgcn_mfma_f32_16x16x32_bf16(aB, bl_, accB, 0, 0, 0); }
#define TAP1(tp, aa)                                                          \
  { v8s bh_ = bhW[(tp) * 256]; v8s bl_ = blW[(tp) * 256];                     \
    acc = __builtin_amdgcn_mfma_f32_16x16x32_bf16(aa, bh_, acc, 0, 0, 0);     \
    acc = __builtin_amdgcn_mfma_f32_16x16x32_bf16(aa, bl_, acc, 0, 0, 0); }

  float dd = 0.0f;

#pragma unroll 1
  for (int side = 0; side < 2; ++side) {
    const float* img = side ? imgS : imgG;
    const float* kp  = side ? kpS : kpG;

    int sx = (int)floorf(kp[n * 2 + 0] * 256.0f) - SIG;
    int sy = (int)floorf(kp[n * 2 + 1] * 256.0f) - SIG;
    sx = min(max(sx, 0), HW - Pp);
    sy = min(max(sy, 0), HW - Pp);
    gp = img + ((size_t)(b * 3) * HW + sy) * HW + sx;

    // prologue: rows 0..5, wave-local (slots 0..5); gathers are global ->
    // no staging sync needed. (Side 1: ordered after side-0 tail reads by
    // the two epilogue barriers.)
    conv1_row_local(wave);              // rows 0..3
    if (wave < 2) conv1_row_local(4 + wave);  // rows 4,5

    __syncthreads();                    // prologue hiP rows 0..5 visible
    // hoisted cache fill: row 0 (slot 0) = ky0 of the first conv2 row.
    v8s n0 = ldA(0, 0), n1 = ldA(0, 1), n2 = ldA(0, 2);

    float gapAcc = 0.0f;

#pragma unroll 1
    for (int i = 0; i < 7; ++i) {       // conv2 rows y = 2i, 2i+1
      __syncthreads();                  // hiP rows 4i..4i+5 visible
      const int base = 4 * i;
      const int s1 = (base + 1) % NSLOT;
      const int s2 = (base + 2) % NSLOT;
      const int s3 = (base + 3) % NSLOT;
      const int s4 = (base + 4) % NSLOT;
      const v8s a00 = n0, a01 = n1, a02 = n2;       // row 4i (accA ky0)
      f32x4 accA = {0.f, 0.f, 0.f, 0.f};
      f32x4 accB = {0.f, 0.f, 0.f, 0.f};
      v8s sh0 = ldA(s2, 0), sh1 = ldA(s2, 1), sh2 = ldA(s2, 2);  // shared row
      {
        TAP2(0, a00, sh0); TAP2(1, a01, sh1); TAP2(2, a02, sh2);
      }
      {
        v8s r10 = ldA(s1, 0), r11 = ldA(s1, 1), r12 = ldA(s1, 2);
        v8s r30 = ldA(s3, 0), r31 = ldA(s3, 1), r32 = ldA(s3, 2);
        TAP2(3, r10, r30); TAP2(4, r11, r31); TAP2(5, r12, r32);
      }
      {
        n0 = ldA(s4, 0); n1 = ldA(s4, 1); n2 = ldA(s4, 2);  // refill cache
        TAP2(6, sh0, n0); TAP2(7, sh1, n1); TAP2(8, sh2, n2);
      }

      // conv1: wave-local rows 4i+6 .. 4i+9 (write slots disjoint from this
      // iteration's ds-read slots mod 9; slot 4i is register-cached).
      // Gathers are global loads -> scheduler may hoist them over the TAP2s.
      {
        const int r = base + 6 + wave;
        if (r <= 30) conv1_row_local(r);
      }

      // gap accumulate in baseline order: y=2i then y=2i+1
      {
        float sA = fmaxf(accA.x + b2v, 0.f) + fmaxf(accA.y + b2v, 0.f) +
                   fmaxf(accA.z + b2v, 0.f);
        if (qq < 3) sA += fmaxf(accA.w + b2v, 0.f);
        gapAcc += sA;
        float sB = fmaxf(accB.x + b2v, 0.f) + fmaxf(accB.y + b2v, 0.f) +
                   fmaxf(accB.z + b2v, 0.f);
        if (qq < 3) sB += fmaxf(accB.w + b2v, 0.f);
        gapAcc += sB;
      }
    }

    // tail: y = 14 (rows 28,29,30 -> slots 1,2,3); n* holds row 28 already
    {
      __syncthreads();                  // row 29/30 writes visible
      f32x4 acc = {0.f, 0.f, 0.f, 0.f};
      TAP1(0, n0); TAP1(1, n1); TAP1(2, n2);
      v8s c0 = ldA(2, 0), c1 = ldA(2, 1), c2 = ldA(2, 2);   // row 29
      TAP1(3, c0); TAP1(4, c1); TAP1(5, c2);
      v8s e0 = ldA(3, 0), e1 = ldA(3, 1), e2 = ldA(3, 2);   // row 30
      TAP1(6, e0); TAP1(7, e1); TAP1(8, e2);
      float s = fmaxf(acc.x + b2v, 0.f) + fmaxf(acc.y + b2v, 0.f) +
                fmaxf(acc.z + b2v, 0.f);
      if (qq < 3) s += fmaxf(acc.w + b2v, 0.f);
      gapAcc += s;
    }

    // reduce gapAcc over kc-quads
    gapAcc += __shfl_down(gapAcc, 32, 64);
    gapAcc += __shfl_down(gapAcc, 16, 64);
    if (lane < 16) gapv[wave * 16 + m16] = gapAcc * (1.0f / 225.0f);
    __syncthreads();

    if (tid < OUTF) {
      float f = blg[tid];
#pragma unroll 16
      for (int i = 0; i < 64; ++i) f = fmaf(gapv[i], ws[WS_WLT + i * OUTF + tid], f);
      if (side == 0) fstash[tid] = f;
      else { float d = f - fstash[tid]; dd = d * d; }
    }
    __syncthreads();
  }

  // block reduction -> one atomicAdd
  dd += __shfl_down(dd, 32, 64);
  dd += __shfl_down(dd, 16, 64);
  dd += __shfl_down(dd, 8, 64);
  dd += __shfl_down(dd, 4, 64);
  dd += __shfl_down(dd, 2, 64);
  dd += __shfl_down(dd, 1, 64);
  if (lane == 0) lred[wave] = dd;
  __syncthreads();
  if (tid == 0) {
    float s = (lred[0] + lred[1]) + (lred[2] + lred[3]);
    atomicAdd(out, s * (1.0f / 131072.0f));
  }
}

extern "C" void kernel_launch(void* const* d_in, const int* in_sizes, int n_in,
                              void* d_out, int out_size, void* d_ws, size_t ws_size,
                              hipStream_t stream) {
  const float* imgG = (const float*)d_in[0];
  const float* imgS = (const float*)d_in[1];
  const float* kpG  = (const float*)d_in[2];
  const float* kpS  = (const float*)d_in[3];
  const float* w1   = (const float*)d_in[4];
  const float* b1   = (const float*)d_in[5];
  const float* w2   = (const float*)d_in[6];
  const float* b2   = (const float*)d_in[7];
  const float* wl   = (const float*)d_in[8];
  const float* bl   = (const float*)d_in[9];
  float* ws  = (float*)d_ws;
  float* out = (float*)d_out;

  hipLaunchKernelGGL(prep_kernel, dim3(32), dim3(256), 0, stream, w1, w2, wl, ws, out);
  hipLaunchKernelGGL(patch_cnn_kernel, dim3(1024), dim3(256), 0, stream,
                     imgG, imgS, kpG, kpS, b1, b2, bl, ws, out);
}

// Round 11
// 177.798 us; speedup vs baseline: 1.0438x; 1.0438x over previous
//
#include <hip/hip_runtime.h>

// Problem constants (fixed by setup_inputs)
#define HW   256
#define Pp   33
#define PPAD 36        // padded patch row (ushort units)
#define OUTF 128
#define SIG  16

// conv1-output plane (bf16) for conv2 MFMA A-operands:
// [rowslot NSLOT][parity 2][col' 16][kc 40] ushort.
// 9-slot ring: iter i ds-READS slots (4i+1..4i+4)%9 (slot 4i is consumed from
// the register cache n*), WRITES rows 4i+6..4i+9 -> slots {4i+6,4i+7,4i+8,4i}%9.
// Read/write sets disjoint -> no mid-iteration barrier.
#define KCP   40
#define PLROW (2 * 16 * KCP)     // 1280 shorts per conv1 row
#define NSLOT 9
#define PLSZ  (NSLOT * PLROW)    // 11520 shorts = 23040 B

// ws layout (float offsets)
#define WS_W1FH 0       // [2 nt][64 lane][8 j] ushort = 512 f (conv1 B-frags hi)
#define WS_W1FL 512     // same, lo
#define WS_BHI  1024    // 18432 ushort = 9216 f (conv2 B-frags hi)
#define WS_BLO  10240   // conv2 B-frags lo
#define WS_WLT  19456   // [64][128] f32 = 8192

typedef __attribute__((ext_vector_type(8))) short v8s;    // 8 bf16
typedef __attribute__((ext_vector_type(4))) float f32x4;  // MFMA acc

__device__ __forceinline__ unsigned short f2bf_rne(float x) {
  unsigned u = __float_as_uint(x);
  unsigned r = (u + 0x7FFFu + ((u >> 16) & 1u)) >> 16;
  return (unsigned short)r;
}
__device__ __forceinline__ float bf2f(unsigned short h) {
  return __uint_as_float(((unsigned)h) << 16);
}
// HW packed f32->bf16 RNE convert: lo16 = bf16(a), hi16 = bf16(b).
// Bit-identical to f2bf_rne for finite inputs (all inputs here are finite).
// No builtin on gfx950 (m240) -> inline asm.
__device__ __forceinline__ unsigned f2bf_pk(float a, float b) {
  unsigned r;
  asm("v_cvt_pk_bf16_f32 %0, %1, %2" : "=v"(r) : "v"(a), "v"(b));
  return r;
}

__global__ __launch_bounds__(256) void prep_kernel(
    const float* __restrict__ w1, const float* __restrict__ w2,
    const float* __restrict__ wl, float* __restrict__ ws,
    float* __restrict__ out) {
  int t = blockIdx.x * 256 + threadIdx.x;
  int stride = gridDim.x * 256;
  if (blockIdx.x == 0 && threadIdx.x == 0) out[0] = 0.0f;
  // conv1 B-frags: k = 8*(l>>4)+j (27-dim padded to 32), ch = 16*nt + (l&15)
  unsigned short* w1h = (unsigned short*)(ws + WS_W1FH);
  unsigned short* w1lo = (unsigned short*)(ws + WS_W1FL);
  for (int i = t; i < 1024; i += stride) {
    int j  = i & 7;
    int l  = (i >> 3) & 63;
    int nt = i >> 9;
    int k  = 8 * (l >> 4) + j;
    int ch = 16 * nt + (l & 15);
    float v = (k < 27) ? w1[ch * 27 + k] : 0.0f;
    unsigned short h = f2bf_rne(v);
    w1h[i]  = h;
    w1lo[i] = f2bf_rne(v - bf2f(h));
  }
  // conv2 B-frags: n(ch)=w*16+(l&15), k(kc)=(l>>4)*8+j, per tap
  unsigned short* bhi = (unsigned short*)(ws + WS_BHI);
  unsigned short* blo = (unsigned short*)(ws + WS_BLO);
  for (int i = t; i < 18432; i += stride) {
    int j  = i & 7;
    int l  = (i >> 3) & 63;
    int w  = (i >> 9) & 3;
    int tp = i >> 11;
    int ch = w * 16 + (l & 15);
    int kc = ((l >> 4) << 3) + j;
    int ky = tp / 3, kx = tp - ky * 3;
    float v = w2[ch * 288 + kc * 9 + ky * 3 + kx];
    unsigned short h = f2bf_rne(v);
    bhi[i] = h;
    blo[i] = f2bf_rne(v - bf2f(h));
  }
  for (int i = t; i < 8192; i += stride) {
    int o = i & 127, ii = i >> 7;
    ws[WS_WLT + i] = wl[o * 64 + ii];
  }
}

// One block per (n,b); both sides in-block; one atomicAdd.
// R11 = R9 (the 71.2us best: LDS patch staging, unrolled load->write staging,
// wave-local conv1, 9-slot ring, dual-chain conv2) + v_cvt_pk_bf16_f32 for
// the two hot bf16 conversion sites (staging pack, conv1 hiP store pack).
// The HW convert is RNE -> bit-identical to the f2bf_rne software rounding
// for finite inputs; op order unchanged; absmax stays 0.0.
// R10's global-gather is REVERTED (VGPR 144 crossed the 128 cliff -> 3
// waves/SIMD, and L2 latency landed on the barrier critical path: 118us).
__global__ __launch_bounds__(256) void patch_cnn_kernel(
    const float* __restrict__ imgG, const float* __restrict__ imgS,
    const float* __restrict__ kpG,  const float* __restrict__ kpS,
    const float* __restrict__ b1g,  const float* __restrict__ b2g,
    const float* __restrict__ blg,  const float* __restrict__ ws,
    float* __restrict__ out) {
  __shared__ __align__(16) unsigned short patch[3 * Pp * PPAD];  // 7128 B
  __shared__ __align__(16) unsigned short hiP[PLSZ];             // 23040 B
  __shared__ float gapv[64];
  __shared__ float fstash[OUTF];
  __shared__ float lred[4];
  // total ~= 30.9 KB

  const int bid  = blockIdx.x;          // grid 1024
  const int n    = bid >> 2;
  const int b    = bid & 3;
  const int tid  = threadIdx.x;
  const int wave = tid >> 6;
  const int lane = tid & 63;

  const int m16 = lane & 15;
  const int qq  = lane >> 4;

  // conv1 per-lane gather offsets: A-frag element j -> k = 8*qq + j
  int  koff[8];
  bool kval[8];
#pragma unroll
  for (int j = 0; j < 8; ++j) {
    int k = 8 * qq + j;
    kval[j] = (k < 27);
    int kk = kval[j] ? k : 0;
    int ci = kk / 9, r2 = kk - ci * 9, ky = r2 / 3, kx = r2 - ky * 3;
    koff[j] = (ci * Pp + ky) * PPAD + kx;          // + r*PPAD + pixel at use
  }

  // conv1 B-frags for BOTH nt slices (each wave does all 4 tiles of its row)
  const v8s* w1fp = (const v8s*)((const unsigned short*)(ws + WS_W1FH));
  const v8s* w1lp = (const v8s*)((const unsigned short*)(ws + WS_W1FL));
  const v8s w1hF0 = w1fp[lane],      w1lF0 = w1lp[lane];
  const v8s w1hF1 = w1fp[64 + lane], w1lF1 = w1lp[64 + lane];
  const float b1v0 = b1g[m16];
  const float b1v1 = b1g[16 + m16];

  // conv2 frag pointers (L2-resident) and bias (N-split by wave)
  const v8s* bhW = (const v8s*)((const unsigned short*)(ws + WS_BHI)) + (wave * 64 + lane);
  const v8s* blW = (const v8s*)((const unsigned short*)(ws + WS_BLO)) + (wave * 64 + lane);
  const float b2v = b2g[wave * 16 + m16];

  // wave-local conv1 for row r: gather 2 A-frags from patch, 4 MFMA tiles,
  // 16 b16 hiP writes (packed pairs via cvt_pk). Values/op-order identical
  // to the original path.
  auto conv1_row_local = [&](int r) {
    const int sl = r % NSLOT;
    const int rbase = r * PPAD;
#pragma unroll
    for (int mtl = 0; mtl < 2; ++mtl) {
      v8s af;
#pragma unroll
      for (int j = 0; j < 8; ++j) {
        unsigned short v =
            kval[j] ? patch[koff[j] + rbase + 16 * mtl + m16] : (unsigned short)0;
        af[j] = (short)v;
      }
      f32x4 z = {0.f, 0.f, 0.f, 0.f};
      f32x4 t0 = __builtin_amdgcn_mfma_f32_16x16x32_bf16(af, w1hF0, z, 0, 0, 0);
      t0 = __builtin_amdgcn_mfma_f32_16x16x32_bf16(af, w1lF0, t0, 0, 0, 0);
      f32x4 t1 = __builtin_amdgcn_mfma_f32_16x16x32_bf16(af, w1hF1, z, 0, 0, 0);
      t1 = __builtin_amdgcn_mfma_f32_16x16x32_bf16(af, w1lF1, t1, 0, 0, 0);
#pragma unroll
      for (int rg = 0; rg < 4; ++rg) {
        int x = 16 * mtl + 4 * qq + rg;   // x=31 garbage, unread slot
        int rowoff = ((sl * 2 + (x & 1)) * 16 + (x >> 1)) * KCP;
        unsigned pk = f2bf_pk(fmaxf(t0[rg] + b1v0, 0.f),
                              fmaxf(t1[rg] + b1v1, 0.f));
        hiP[rowoff + m16]      = (unsigned short)pk;
        hiP[rowoff + 16 + m16] = (unsigned short)(pk >> 16);
      }
    }
  };

  // conv2 A-operand load: (row-slot sk in [0,NSLOT), tap kx)
  auto ldA = [&](int sk, int kx) -> v8s {
    const int p = kx & 1;
    int cp = m16 + (kx >> 1); if (cp > 15) cp = 15;   // xo=15 is pad, discarded
    return *(const v8s*)&hiP[((sk * 2 + p) * 16 + cp) * KCP + qq * 8];
  };

// dual-row tap: chain order inside each acc identical to baseline (hi, lo)
#define TAP2(tp, aA, aB)                                                      \
  { v8s bh_ = bhW[(tp) * 256]; v8s bl_ = blW[(tp) * 256];                     \
    accA = __builtin_amdgcn_mfma_f32_16x16x32_bf16(aA, bh_, accA, 0, 0, 0);   \
    accB = __builtin_amdgcn_mfma_f32_16x16x32_bf16(aB, bh_, accB, 0, 0, 0);   \
    accA = __builtin_amdgcn_mfma_f32_16x16x32_bf16(aA, bl_, accA, 0, 0, 0);   \
    accB = __builtin_amdgcn_mfma_f32_16x16x32_bf16(aB, bl_, accB, 0, 0, 0); }
#define TAP1(tp, aa)                                                          \
  { v8s bh_ = bhW[(tp) * 256]; v8s bl_ = blW[(tp) * 256];                     \
    acc = __builtin_amdgcn_mfma_f32_16x16x32_bf16(aa, bh_, acc, 0, 0, 0);     \
    acc = __builtin_amdgcn_mfma_f32_16x16x32_bf16(aa, bl_, acc, 0, 0, 0); }

  float dd = 0.0f;

#pragma unroll 1
  for (int side = 0; side < 2; ++side) {
    const float* img = side ? imgS : imgG;
    const float* kp  = side ? kpS : kpG;

    int sx = (int)floorf(kp[n * 2 + 0] * 256.0f) - SIG;
    int sy = (int)floorf(kp[n * 2 + 1] * 256.0f) - SIG;
    sx = min(max(sx, 0), HW - Pp);
    sy = min(max(sy, 0), HW - Pp);

    // stage patch as bf16 pairs, UNROLLED: load phase (7 batched global
    // loads) -> write phase. 1782 float2-pairs over 256 threads = 7 trips
    // (trip 6 guarded: only tid<246 valid). Values identical to the old loop
    // (cvt_pk = same RNE bits as the software pack).
    {
      float svx[7], svy[7];
#pragma unroll
      for (int k = 0; k < 7; ++k) {
        int i = tid + k * 256;
        float vx = 0.f, vy = 0.f;
        if (k < 6 || i < 1782) {
          int e  = 2 * i;
          int ci = e / (Pp * PPAD);
          int r2 = e - ci * (Pp * PPAD);
          int r  = r2 / PPAD;
          int cc = r2 - r * PPAD;
          const float* rowp = &img[((b * 3 + ci) * HW + (sy + r)) * HW + sx];
          if (cc < 32) { float2 v = *(const float2*)(rowp + cc); vx = v.x; vy = v.y; }
          else if (cc == 32) { vx = rowp[32]; }
        }
        svx[k] = vx; svy[k] = vy;
      }
#pragma unroll
      for (int k = 0; k < 7; ++k) {
        int i = tid + k * 256;
        if (k < 6 || i < 1782) {
          *(unsigned*)&patch[2 * i] = f2bf_pk(svx[k], svy[k]);
        }
      }
    }
    __syncthreads();                    // patch visible
    // prologue: rows 0..5, wave-local (slots 0..5)
    conv1_row_local(wave);              // rows 0..3
    if (wave < 2) conv1_row_local(4 + wave);  // rows 4,5

    __syncthreads();                    // prologue hiP rows 0..5 visible
    // hoisted cache fill: row 0 (slot 0) = ky0 of the first conv2 row.
    v8s n0 = ldA(0, 0), n1 = ldA(0, 1), n2 = ldA(0, 2);

    float gapAcc = 0.0f;

#pragma unroll 1
    for (int i = 0; i < 7; ++i) {       // conv2 rows y = 2i, 2i+1
      __syncthreads();                  // hiP rows 4i..4i+5 visible
      const int base = 4 * i;
      const int s1 = (base + 1) % NSLOT;
      const int s2 = (base + 2) % NSLOT;
      const int s3 = (base + 3) % NSLOT;
      const int s4 = (base + 4) % NSLOT;
      const v8s a00 = n0, a01 = n1, a02 = n2;       // row 4i (accA ky0)
      f32x4 accA = {0.f, 0.f, 0.f, 0.f};
      f32x4 accB = {0.f, 0.f, 0.f, 0.f};
      v8s sh0 = ldA(s2, 0), sh1 = ldA(s2, 1), sh2 = ldA(s2, 2);  // shared row
      {
        TAP2(0, a00, sh0); TAP2(1, a01, sh1); TAP2(2, a02, sh2);
      }
      {
        v8s r10 = ldA(s1, 0), r11 = ldA(s1, 1), r12 = ldA(s1, 2);
        v8s r30 = ldA(s3, 0), r31 = ldA(s3, 1), r32 = ldA(s3, 2);
        TAP2(3, r10, r30); TAP2(4, r11, r31); TAP2(5, r12, r32);
      }
      {
        n0 = ldA(s4, 0); n1 = ldA(s4, 1); n2 = ldA(s4, 2);  // refill cache
        TAP2(6, sh0, n0); TAP2(7, sh1, n1); TAP2(8, sh2, n2);
      }

      // conv1: wave-local rows 4i+6 .. 4i+9 (write slots disjoint from this
      // iteration's ds-read slots mod 9; slot 4i is register-cached)
      {
        const int r = base + 6 + wave;
        if (r <= 30) conv1_row_local(r);
      }

      // gap accumulate in baseline order: y=2i then y=2i+1
      {
        float sA = fmaxf(accA.x + b2v, 0.f) + fmaxf(accA.y + b2v, 0.f) +
                   fmaxf(accA.z + b2v, 0.f);
        if (qq < 3) sA += fmaxf(accA.w + b2v, 0.f);
        gapAcc += sA;
        float sB = fmaxf(accB.x + b2v, 0.f) + fmaxf(accB.y + b2v, 0.f) +
                   fmaxf(accB.z + b2v, 0.f);
        if (qq < 3) sB += fmaxf(accB.w + b2v, 0.f);
        gapAcc += sB;
      }
    }

    // tail: y = 14 (rows 28,29,30 -> slots 1,2,3); n* holds row 28 already
    {
      __syncthreads();                  // row 29/30 writes visible
      f32x4 acc = {0.f, 0.f, 0.f, 0.f};
      TAP1(0, n0); TAP1(1, n1); TAP1(2, n2);
      v8s c0 = ldA(2, 0), c1 = ldA(2, 1), c2 = ldA(2, 2);   // row 29
      TAP1(3, c0); TAP1(4, c1); TAP1(5, c2);
      v8s e0 = ldA(3, 0), e1 = ldA(3, 1), e2 = ldA(3, 2);   // row 30
      TAP1(6, e0); TAP1(7, e1); TAP1(8, e2);
      float s = fmaxf(acc.x + b2v, 0.f) + fmaxf(acc.y + b2v, 0.f) +
                fmaxf(acc.z + b2v, 0.f);
      if (qq < 3) s += fmaxf(acc.w + b2v, 0.f);
      gapAcc += s;
    }

    // reduce gapAcc over kc-quads
    gapAcc += __shfl_down(gapAcc, 32, 64);
    gapAcc += __shfl_down(gapAcc, 16, 64);
    if (lane < 16) gapv[wave * 16 + m16] = gapAcc * (1.0f / 225.0f);
    __syncthreads();

    if (tid < OUTF) {
      float f = blg[tid];
#pragma unroll 16
      for (int i = 0; i < 64; ++i) f = fmaf(gapv[i], ws[WS_WLT + i * OUTF + tid], f);
      if (side == 0) fstash[tid] = f;
      else { float d = f - fstash[tid]; dd = d * d; }
    }
    __syncthreads();
  }

  // block reduction -> one atomicAdd
  dd += __shfl_down(dd, 32, 64);
  dd += __shfl_down(dd, 16, 64);
  dd += __shfl_down(dd, 8, 64);
  dd += __shfl_down(dd, 4, 64);
  dd += __shfl_down(dd, 2, 64);
  dd += __shfl_down(dd, 1, 64);
  if (lane == 0) lred[wave] = dd;
  __syncthreads();
  if (tid == 0) {
    float s = (lred[0] + lred[1]) + (lred[2] + lred[3]);
    atomicAdd(out, s * (1.0f / 131072.0f));
  }
}

extern "C" void kernel_launch(void* const* d_in, const int* in_sizes, int n_in,
                              void* d_out, int out_size, void* d_ws, size_t ws_size,
                              hipStream_t stream) {
  const float* imgG = (const float*)d_in[0];
  const float* imgS = (const float*)d_in[1];
  const float* kpG  = (const float*)d_in[2];
  const float* kpS  = (const float*)d_in[3];
  const float* w1   = (const float*)d_in[4];
  const float* b1   = (const float*)d_in[5];
  const float* w2   = (const float*)d_in[6];
  const float* b2   = (const float*)d_in[7];
  const float* wl   = (const float*)d_in[8];
  const float* bl   = (const float*)d_in[9];
  float* ws  = (float*)d_ws;
  float* out = (float*)d_out;

  hipLaunchKernelGGL(prep_kernel, dim3(32), dim3(256), 0, stream, w1, w2, wl, ws, out);
  hipLaunchKernelGGL(patch_cnn_kernel, dim3(1024), dim3(256), 0, stream,
                     imgG, imgS, kpG, kpS, b1, b2, bl, ws, out);
}

// Round 12
// 135.969 us; speedup vs baseline: 1.3649x; 1.3076x over previous
//
#include <hip/hip_runtime.h>

// Problem constants (fixed by setup_inputs)
#define HW   256
#define Pp   33
#define PPAD 36        // padded patch row (ushort units)
#define OUTF 128
#define SIG  16

// conv1-output plane (bf16) for conv2 MFMA A-operands:
// [rowslot NSLOT][parity 2][col' 16][kc 40] ushort.
// 9-slot ring: iter i ds-READS slots (4i+1..4i+4)%9 (slot 4i is consumed from
// the register cache n*), WRITES rows 4i+6..4i+9 -> slots {4i+6,4i+7,4i+8,4i}%9.
// Read/write sets disjoint -> no mid-iteration barrier.
#define KCP   40
#define PLROW (2 * 16 * KCP)     // 1280 shorts per conv1 row
#define NSLOT 9
#define PLSZ  (NSLOT * PLROW)    // 11520 shorts = 23040 B

// ws layout (float offsets)
#define WS_W1FH 0       // [2 nt][64 lane][8 j] ushort = 512 f (conv1 B-frags hi)
#define WS_W1FL 512     // same, lo
#define WS_BHI  1024    // 18432 ushort = 9216 f (conv2 B-frags hi)
#define WS_BLO  10240   // conv2 B-frags lo
#define WS_WLT  19456   // [64][128] f32 = 8192

typedef __attribute__((ext_vector_type(8))) short v8s;    // 8 bf16
typedef __attribute__((ext_vector_type(4))) float f32x4;  // MFMA acc

__device__ __forceinline__ unsigned short f2bf_rne(float x) {
  unsigned u = __float_as_uint(x);
  unsigned r = (u + 0x7FFFu + ((u >> 16) & 1u)) >> 16;
  return (unsigned short)r;
}
__device__ __forceinline__ float bf2f(unsigned short h) {
  return __uint_as_float(((unsigned)h) << 16);
}

__global__ __launch_bounds__(256) void prep_kernel(
    const float* __restrict__ w1, const float* __restrict__ w2,
    const float* __restrict__ wl, float* __restrict__ ws,
    float* __restrict__ out) {
  int t = blockIdx.x * 256 + threadIdx.x;
  int stride = gridDim.x * 256;
  if (blockIdx.x == 0 && threadIdx.x == 0) out[0] = 0.0f;
  // conv1 B-frags: k = 8*(l>>4)+j (27-dim padded to 32), ch = 16*nt + (l&15)
  unsigned short* w1h = (unsigned short*)(ws + WS_W1FH);
  unsigned short* w1lo = (unsigned short*)(ws + WS_W1FL);
  for (int i = t; i < 1024; i += stride) {
    int j  = i & 7;
    int l  = (i >> 3) & 63;
    int nt = i >> 9;
    int k  = 8 * (l >> 4) + j;
    int ch = 16 * nt + (l & 15);
    float v = (k < 27) ? w1[ch * 27 + k] : 0.0f;
    unsigned short h = f2bf_rne(v);
    w1h[i]  = h;
    w1lo[i] = f2bf_rne(v - bf2f(h));
  }
  // conv2 B-frags: n(ch)=w*16+(l&15), k(kc)=(l>>4)*8+j, per tap
  unsigned short* bhi = (unsigned short*)(ws + WS_BHI);
  unsigned short* blo = (unsigned short*)(ws + WS_BLO);
  for (int i = t; i < 18432; i += stride) {
    int j  = i & 7;
    int l  = (i >> 3) & 63;
    int w  = (i >> 9) & 3;
    int tp = i >> 11;
    int ch = w * 16 + (l & 15);
    int kc = ((l >> 4) << 3) + j;
    int ky = tp / 3, kx = tp - ky * 3;
    float v = w2[ch * 288 + kc * 9 + ky * 3 + kx];
    unsigned short h = f2bf_rne(v);
    bhi[i] = h;
    blo[i] = f2bf_rne(v - bf2f(h));
  }
  for (int i = t; i < 8192; i += stride) {
    int o = i & 127, ii = i >> 7;
    ws[WS_WLT + i] = wl[o * 64 + ii];
  }
}

// One block per (n,b); both sides in-block; one atomicAdd.
// R12 = R9 verbatim (best measured: patch 71.2us, total 136.0us, absmax 0.0).
// R10 (global gather) and R11 (cvt_pk asm) both crossed the 128-VGPR cliff
// (VGPR 144/136 -> 3 waves/SIMD) and regressed ~1.6x; this kernel sits at
// VGPR 124 and any added live state is a regression. Structure:
//  - LDS patch staging, UNROLLED load-phase -> write-phase (7 static trips)
//  - wave-local conv1 (gather from patch, 4 MFMA tiles, hiP stores)
//  - 9-slot hiP ring, 1 barrier per 2 conv2 rows, s4 register cache
//  - conv2 dual-row independent chains (TAP2), baseline op order per chain
__global__ __launch_bounds__(256) void patch_cnn_kernel(
    const float* __restrict__ imgG, const float* __restrict__ imgS,
    const float* __restrict__ kpG,  const float* __restrict__ kpS,
    const float* __restrict__ b1g,  const float* __restrict__ b2g,
    const float* __restrict__ blg,  const float* __restrict__ ws,
    float* __restrict__ out) {
  __shared__ __align__(16) unsigned short patch[3 * Pp * PPAD];  // 7128 B
  __shared__ __align__(16) unsigned short hiP[PLSZ];             // 23040 B
  __shared__ float gapv[64];
  __shared__ float fstash[OUTF];
  __shared__ float lred[4];
  // total ~= 30.9 KB

  const int bid  = blockIdx.x;          // grid 1024
  const int n    = bid >> 2;
  const int b    = bid & 3;
  const int tid  = threadIdx.x;
  const int wave = tid >> 6;
  const int lane = tid & 63;

  const int m16 = lane & 15;
  const int qq  = lane >> 4;

  // conv1 per-lane gather offsets: A-frag element j -> k = 8*qq + j
  int  koff[8];
  bool kval[8];
#pragma unroll
  for (int j = 0; j < 8; ++j) {
    int k = 8 * qq + j;
    kval[j] = (k < 27);
    int kk = kval[j] ? k : 0;
    int ci = kk / 9, r2 = kk - ci * 9, ky = r2 / 3, kx = r2 - ky * 3;
    koff[j] = (ci * Pp + ky) * PPAD + kx;          // + r*PPAD + pixel at use
  }

  // conv1 B-frags for BOTH nt slices (each wave does all 4 tiles of its row)
  const v8s* w1fp = (const v8s*)((const unsigned short*)(ws + WS_W1FH));
  const v8s* w1lp = (const v8s*)((const unsigned short*)(ws + WS_W1FL));
  const v8s w1hF0 = w1fp[lane],      w1lF0 = w1lp[lane];
  const v8s w1hF1 = w1fp[64 + lane], w1lF1 = w1lp[64 + lane];
  const float b1v0 = b1g[m16];
  const float b1v1 = b1g[16 + m16];

  // conv2 frag pointers (L2-resident) and bias (N-split by wave)
  const v8s* bhW = (const v8s*)((const unsigned short*)(ws + WS_BHI)) + (wave * 64 + lane);
  const v8s* blW = (const v8s*)((const unsigned short*)(ws + WS_BLO)) + (wave * 64 + lane);
  const float b2v = b2g[wave * 16 + m16];

  // wave-local conv1 for row r: gather 2 A-frags from patch, 4 MFMA tiles,
  // 16 b16 hiP writes. Values/op-order identical to the original path.
  auto conv1_row_local = [&](int r) {
    const int sl = r % NSLOT;
    const int rbase = r * PPAD;
#pragma unroll
    for (int mtl = 0; mtl < 2; ++mtl) {
      v8s af;
#pragma unroll
      for (int j = 0; j < 8; ++j) {
        unsigned short v =
            kval[j] ? patch[koff[j] + rbase + 16 * mtl + m16] : (unsigned short)0;
        af[j] = (short)v;
      }
      f32x4 z = {0.f, 0.f, 0.f, 0.f};
      f32x4 t0 = __builtin_amdgcn_mfma_f32_16x16x32_bf16(af, w1hF0, z, 0, 0, 0);
      t0 = __builtin_amdgcn_mfma_f32_16x16x32_bf16(af, w1lF0, t0, 0, 0, 0);
      f32x4 t1 = __builtin_amdgcn_mfma_f32_16x16x32_bf16(af, w1hF1, z, 0, 0, 0);
      t1 = __builtin_amdgcn_mfma_f32_16x16x32_bf16(af, w1lF1, t1, 0, 0, 0);
#pragma unroll
      for (int rg = 0; rg < 4; ++rg) {
        int x = 16 * mtl + 4 * qq + rg;   // x=31 garbage, unread slot
        int rowoff = ((sl * 2 + (x & 1)) * 16 + (x >> 1)) * KCP;
        hiP[rowoff + m16]      = f2bf_rne(fmaxf(t0[rg] + b1v0, 0.f));
        hiP[rowoff + 16 + m16] = f2bf_rne(fmaxf(t1[rg] + b1v1, 0.f));
      }
    }
  };

  // conv2 A-operand load: (row-slot sk in [0,NSLOT), tap kx)
  auto ldA = [&](int sk, int kx) -> v8s {
    const int p = kx & 1;
    int cp = m16 + (kx >> 1); if (cp > 15) cp = 15;   // xo=15 is pad, discarded
    return *(const v8s*)&hiP[((sk * 2 + p) * 16 + cp) * KCP + qq * 8];
  };

// dual-row tap: chain order inside each acc identical to baseline (hi, lo)
#define TAP2(tp, aA, aB)                                                      \
  { v8s bh_ = bhW[(tp) * 256]; v8s bl_ = blW[(tp) * 256];                     \
    accA = __builtin_amdgcn_mfma_f32_16x16x32_bf16(aA, bh_, accA, 0, 0, 0);   \
    accB = __builtin_amdgcn_mfma_f32_16x16x32_bf16(aB, bh_, accB, 0, 0, 0);   \
    accA = __builtin_amdgcn_mfma_f32_16x16x32_bf16(aA, bl_, accA, 0, 0, 0);   \
    accB = __builtin_amdgcn_mfma_f32_16x16x32_bf16(aB, bl_, accB, 0, 0, 0); }
#define TAP1(tp, aa)                                                          \
  { v8s bh_ = bhW[(tp) * 256]; v8s bl_ = blW[(tp) * 256];                     \
    acc = __builtin_amdgcn_mfma_f32_16x16x32_bf16(aa, bh_, acc, 0, 0, 0);     \
    acc = __builtin_amdgcn_mfma_f32_16x16x32_bf16(aa, bl_, acc, 0, 0, 0); }

  float dd = 0.0f;

#pragma unroll 1
  for (int side = 0; side < 2; ++side) {
    const float* img = side ? imgS : imgG;
    const float* kp  = side ? kpS : kpG;

    int sx = (int)floorf(kp[n * 2 + 0] * 256.0f) - SIG;
    int sy = (int)floorf(kp[n * 2 + 1] * 256.0f) - SIG;
    sx = min(max(sx, 0), HW - Pp);
    sy = min(max(sy, 0), HW - Pp);

    // stage patch as bf16 pairs, UNROLLED: load phase (7 batched global
    // loads) -> write phase. 1782 float2-pairs over 256 threads = 7 trips
    // (trip 6 guarded: only tid<246 valid). Values identical to the old loop.
    {
      float svx[7], svy[7];
#pragma unroll
      for (int k = 0; k < 7; ++k) {
        int i = tid + k * 256;
        float vx = 0.f, vy = 0.f;
        if (k < 6 || i < 1782) {
          int e  = 2 * i;
          int ci = e / (Pp * PPAD);
          int r2 = e - ci * (Pp * PPAD);
          int r  = r2 / PPAD;
          int cc = r2 - r * PPAD;
          const float* rowp = &img[((b * 3 + ci) * HW + (sy + r)) * HW + sx];
          if (cc < 32) { float2 v = *(const float2*)(rowp + cc); vx = v.x; vy = v.y; }
          else if (cc == 32) { vx = rowp[32]; }
        }
        svx[k] = vx; svy[k] = vy;
      }
#pragma unroll
      for (int k = 0; k < 7; ++k) {
        int i = tid + k * 256;
        if (k < 6 || i < 1782) {
          unsigned pk = (unsigned)f2bf_rne(svx[k]) | ((unsigned)f2bf_rne(svy[k]) << 16);
          *(unsigned*)&patch[2 * i] = pk;
        }
      }
    }
    __syncthreads();                    // patch visible
    // prologue: rows 0..5, wave-local (slots 0..5)
    conv1_row_local(wave);              // rows 0..3
    if (wave < 2) conv1_row_local(4 + wave);  // rows 4,5

    __syncthreads();                    // prologue hiP rows 0..5 visible
    // hoisted cache fill: row 0 (slot 0) = ky0 of the first conv2 row.
    v8s n0 = ldA(0, 0), n1 = ldA(0, 1), n2 = ldA(0, 2);

    float gapAcc = 0.0f;

#pragma unroll 1
    for (int i = 0; i < 7; ++i) {       // conv2 rows y = 2i, 2i+1
      __syncthreads();                  // hiP rows 4i..4i+5 visible
      const int base = 4 * i;
      const int s1 = (base + 1) % NSLOT;
      const int s2 = (base + 2) % NSLOT;
      const int s3 = (base + 3) % NSLOT;
      const int s4 = (base + 4) % NSLOT;
      const v8s a00 = n0, a01 = n1, a02 = n2;       // row 4i (accA ky0)
      f32x4 accA = {0.f, 0.f, 0.f, 0.f};
      f32x4 accB = {0.f, 0.f, 0.f, 0.f};
      v8s sh0 = ldA(s2, 0), sh1 = ldA(s2, 1), sh2 = ldA(s2, 2);  // shared row
      {
        TAP2(0, a00, sh0); TAP2(1, a01, sh1); TAP2(2, a02, sh2);
      }
      {
        v8s r10 = ldA(s1, 0), r11 = ldA(s1, 1), r12 = ldA(s1, 2);
        v8s r30 = ldA(s3, 0), r31 = ldA(s3, 1), r32 = ldA(s3, 2);
        TAP2(3, r10, r30); TAP2(4, r11, r31); TAP2(5, r12, r32);
      }
      {
        n0 = ldA(s4, 0); n1 = ldA(s4, 1); n2 = ldA(s4, 2);  // refill cache
        TAP2(6, sh0, n0); TAP2(7, sh1, n1); TAP2(8, sh2, n2);
      }

      // conv1: wave-local rows 4i+6 .. 4i+9 (write slots disjoint from this
      // iteration's ds-read slots mod 9; slot 4i is register-cached)
      {
        const int r = base + 6 + wave;
        if (r <= 30) conv1_row_local(r);
      }

      // gap accumulate in baseline order: y=2i then y=2i+1
      {
        float sA = fmaxf(accA.x + b2v, 0.f) + fmaxf(accA.y + b2v, 0.f) +
                   fmaxf(accA.z + b2v, 0.f);
        if (qq < 3) sA += fmaxf(accA.w + b2v, 0.f);
        gapAcc += sA;
        float sB = fmaxf(accB.x + b2v, 0.f) + fmaxf(accB.y + b2v, 0.f) +
                   fmaxf(accB.z + b2v, 0.f);
        if (qq < 3) sB += fmaxf(accB.w + b2v, 0.f);
        gapAcc += sB;
      }
    }

    // tail: y = 14 (rows 28,29,30 -> slots 1,2,3); n* holds row 28 already
    {
      __syncthreads();                  // row 29/30 writes visible
      f32x4 acc = {0.f, 0.f, 0.f, 0.f};
      TAP1(0, n0); TAP1(1, n1); TAP1(2, n2);
      v8s c0 = ldA(2, 0), c1 = ldA(2, 1), c2 = ldA(2, 2);   // row 29
      TAP1(3, c0); TAP1(4, c1); TAP1(5, c2);
      v8s e0 = ldA(3, 0), e1 = ldA(3, 1), e2 = ldA(3, 2);   // row 30
      TAP1(6, e0); TAP1(7, e1); TAP1(8, e2);
      float s = fmaxf(acc.x + b2v, 0.f) + fmaxf(acc.y + b2v, 0.f) +
                fmaxf(acc.z + b2v, 0.f);
      if (qq < 3) s += fmaxf(acc.w + b2v, 0.f);
      gapAcc += s;
    }

    // reduce gapAcc over kc-quads
    gapAcc += __shfl_down(gapAcc, 32, 64);
    gapAcc += __shfl_down(gapAcc, 16, 64);
    if (lane < 16) gapv[wave * 16 + m16] = gapAcc * (1.0f / 225.0f);
    __syncthreads();

    if (tid < OUTF) {
      float f = blg[tid];
#pragma unroll 16
      for (int i = 0; i < 64; ++i) f = fmaf(gapv[i], ws[WS_WLT + i * OUTF + tid], f);
      if (side == 0) fstash[tid] = f;
      else { float d = f - fstash[tid]; dd = d * d; }
    }
    __syncthreads();
  }

  // block reduction -> one atomicAdd
  dd += __shfl_down(dd, 32, 64);
  dd += __shfl_down(dd, 16, 64);
  dd += __shfl_down(dd, 8, 64);
  dd += __shfl_down(dd, 4, 64);
  dd += __shfl_down(dd, 2, 64);
  dd += __shfl_down(dd, 1, 64);
  if (lane == 0) lred[wave] = dd;
  __syncthreads();
  if (tid == 0) {
    float s = (lred[0] + lred[1]) + (lred[2] + lred[3]);
    atomicAdd(out, s * (1.0f / 131072.0f));
  }
}

extern "C" void kernel_launch(void* const* d_in, const int* in_sizes, int n_in,
                              void* d_out, int out_size, void* d_ws, size_t ws_size,
                              hipStream_t stream) {
  const float* imgG = (const float*)d_in[0];
  const float* imgS = (const float*)d_in[1];
  const float* kpG  = (const float*)d_in[2];
  const float* kpS  = (const float*)d_in[3];
  const float* w1   = (const float*)d_in[4];
  const float* b1   = (const float*)d_in[5];
  const float* w2   = (const float*)d_in[6];
  const float* b2   = (const float*)d_in[7];
  const float* wl   = (const float*)d_in[8];
  const float* bl   = (const float*)d_in[9];
  float* ws  = (float*)d_ws;
  float* out = (float*)d_out;

  hipLaunchKernelGGL(prep_kernel, dim3(32), dim3(256), 0, stream, w1, w2, wl, ws, out);
  hipLaunchKernelGGL(patch_cnn_kernel, dim3(1024), dim3(256), 0, stream,
                     imgG, imgS, kpG, kpS, b1, b2, bl, ws, out);
}